// Round 15
// baseline (4261.525 us; speedup 1.0000x reference)
//
#include <hip/hip_runtime.h>

// ---------------------------------------------------------------------------
// 2-layer GRU, H=256, seq=64, rows = B*N = 2048.
// PIPELINE DECOMPOSITION (no inter-WG barriers): 64 pairs x 32 rows.
//   L0-WG (bid p < 64): full layer-0 recurrence for rows [32p,32p+32), all
//     768 gate dims. h0 state lives in its LDS (HT). Streams wi0+wh0 from
//     L2. Publishes h0(t) A-frags to a depth-4 ring (backpressure via a
//     consumed-counter; stays <=4 steps ahead).
//   L1-WG (bid 64+p): consumes h0(t) (producer ahead -> poll immediate),
//     own h1 recurrence in LDS, streams wi1+wh1, writes out.
// Only sync: 1-producer/1-consumer flag pair per pipeline. Pair members at
// bids {p, p+64} == p (mod 8) -> same XCD; ring ops sc0 (local L2) when the
// runtime XCC vote confirms, else sc0 sc1 (correct under any placement).
// r14 BUGFIX: hidden-weight n-gate product accumulates into aH (not aN) so
// the epilogue computes n = tanh((gi_n+bi_n) + r*(gh_n+bh_n)).
// ---------------------------------------------------------------------------

typedef __attribute__((ext_vector_type(8))) __bf16 bf8;
typedef __attribute__((ext_vector_type(8))) unsigned short u16x8;
typedef __attribute__((ext_vector_type(4))) unsigned u32x4;
typedef __attribute__((ext_vector_type(4))) float f32x4;

#define MFMA16(A, B, C) __builtin_amdgcn_mfma_f32_16x16x32_bf16((A), (B), (C), 0, 0, 0)

#define ROWS 2048
#define HID 256
#define NW 768
#define SLOT (ROWS * HID)                       // 524288
#define OUT_HID_OFF ((size_t)64 * ROWS * HID)   // 33554432
#define RDEPTH 4
#define RSLOTU 8192                             // u16 per ring slot (16 KB)

static __device__ __forceinline__ float b2f(unsigned short u) {
  union { unsigned u32; float f; } v;
  v.u32 = ((unsigned)u) << 16;
  return v.f;
}
static __device__ __forceinline__ unsigned short f2b(float f) {
  unsigned u = __float_as_uint(f);
  u += 0x7fffu + ((u >> 16) & 1u);  // RNE
  return (unsigned short)(u >> 16);
}
static __device__ __forceinline__ float sigm(float x) {
  return 1.0f / (1.0f + __expf(-x));
}
static __device__ __forceinline__ float tanh_fast(float x) {
  x = fminf(15.0f, fmaxf(-15.0f, x));
  float e = __expf(2.0f * x);
  return (e - 1.0f) / (e + 1.0f);
}
static __device__ __forceinline__ float ldin(const void* p, int i, int f32w) {
  return f32w ? ((const float*)p)[i] : b2f(((const unsigned short*)p)[i]);
}
static __device__ __forceinline__ void stout(void* p, size_t i, float v, int f32w) {
  if (f32w) ((float*)p)[i] = v;
  else ((unsigned short*)p)[i] = f2b(v);
}

// Coherent 16B ring ops. fast: sc0 (local XCD L2 — vote-verified). slow:
// sc0 sc1 (device coherence point). Ordering via explicit vmcnt drain.
static __device__ __forceinline__ bf8 ld16b(const void* p, int fast) {
  union { u32x4 u; bf8 b; } r;
  if (fast)
    asm volatile("global_load_dwordx4 %0, %1, off sc0"
                 : "=v"(r.u) : "v"(p) : "memory");
  else
    asm volatile("global_load_dwordx4 %0, %1, off sc0 sc1"
                 : "=v"(r.u) : "v"(p) : "memory");
  return r.b;
}
static __device__ __forceinline__ void st16c(void* p, u32x4 v, int fast) {
  if (fast)
    asm volatile("global_store_dwordx4 %0, %1, off sc0"
                 : : "v"(p), "v"(v) : "memory");
  else
    asm volatile("global_store_dwordx4 %0, %1, off sc0 sc1"
                 : : "v"(p), "v"(v) : "memory");
}
#define VMDRAIN do { asm volatile("s_waitcnt vmcnt(0)" ::: "memory"); \
                     __builtin_amdgcn_sched_barrier(0); } while (0)

// --------------------------- dtype probe -----------------------------------
__global__ void probe_dtype(const unsigned short* x, unsigned* flag) {
  if (blockIdx.x != 0 || threadIdx.x != 0) return;
  int cnt = 0;
  for (int i = 0; i < 256; ++i) {
    float v = b2f(x[i]);
    if (v == v && fabsf(v) <= 8.0f) cnt++;
  }
  *flag = (cnt >= 250) ? 0u : 1u;  // 0 = bf16 world, 1 = f32 world
}

// --------------------------- weight pre-pack -------------------------------
// packed[nb][kk][lane][e] = W[kk*32 + (lane>>4)*8 + e][nb*16 + (lane&15)]
__global__ void pack_w(const void* __restrict__ W,
                       unsigned short* __restrict__ P, int KK,
                       const unsigned* __restrict__ flag) {
  int i = blockIdx.x * blockDim.x + threadIdx.x;
  int total = 48 * KK * 64;
  if (i >= total) return;
  int f32w = (int)*flag;
  int l = i & 63;
  int kk = (i >> 6) % KK;
  int nb = i / (64 * KK);
  int n = nb * 16 + (l & 15);
  int k0 = kk * 32 + (l >> 4) * 8;
  u16x8 tmp;
#pragma unroll
  for (int e = 0; e < 8; ++e) tmp[e] = f2b(ldin(W, (k0 + e) * NW + n, f32w));
  *(u16x8*)(P + (size_t)i * 8) = tmp;
}

// --------------------------- main kernel -----------------------------------
__global__ void __launch_bounds__(256, 1) gru_main(
    const void* __restrict__ x,
    const void* __restrict__ bi0, const void* __restrict__ bh0,
    const void* __restrict__ bi1, const void* __restrict__ bh1,
    const unsigned short* __restrict__ pwi0, const unsigned short* __restrict__ pwh0,
    const unsigned short* __restrict__ pwi1, const unsigned short* __restrict__ pwh1,
    void* __restrict__ out,
    unsigned short* __restrict__ ring,
    unsigned* __restrict__ flags, const unsigned* __restrict__ flag) {
  // HT: this WG's OWN h state, [32 rows][264 u16] (stride 528 B, 16B-aligned).
  __shared__ __align__(16) unsigned short HT[32 * 264];

  const int f32w = (int)*flag;
  const int tid = threadIdx.x;
  const int lane = tid & 63;
  const int wid = tid >> 6;
  const int bid = blockIdx.x;
  const int isL1 = bid >= 64;
  const int p = isL1 ? bid - 64 : bid;
  const int rb = p * 32;
  const int koff = (lane >> 4) * 8;
  const int rl = (lane >> 4) * 4;

  unsigned* fb = flags + (size_t)p * 64;
  unsigned* prodF = fb;        // h0 slots published by L0
  unsigned* consF = fb + 32;   // h0 slots consumed (drained) by L1

  // ---- placement vote: do the 2 pair members share an XCD? ----
  unsigned xcc;
  asm volatile("s_getreg_b32 %0, hwreg(HW_REG_XCC_ID)" : "=s"(xcc));
  if (tid == 0) {
    __hip_atomic_fetch_or(fb + 48, 1u << (xcc & 31u), __ATOMIC_RELAXED,
                          __HIP_MEMORY_SCOPE_AGENT);
    __hip_atomic_fetch_add(fb + 49, 1u, __ATOMIC_RELEASE,
                           __HIP_MEMORY_SCOPE_AGENT);
    while (__hip_atomic_load(fb + 49, __ATOMIC_RELAXED,
                             __HIP_MEMORY_SCOPE_AGENT) < 2u)
      __builtin_amdgcn_s_sleep(1);
  }
  __syncthreads();
  const unsigned xm = __hip_atomic_load(fb + 48, __ATOMIC_RELAXED,
                                        __HIP_MEMORY_SCOPE_AGENT);
  const int fast = (xm != 0u) && ((xm & (xm - 1u)) == 0u);

  unsigned short* ringp = ring + (size_t)p * (RDEPTH * RSLOTU);

  // Per-wave gate columns: wave owns h-dims [wid*64, wid*64+64) via blocks
  // nb = gate*16 + wid*4 + q, q=0..3. Bias-derived acc inits:
  const void* bI = isL1 ? bi1 : bi0;
  const void* bH = isL1 ? bh1 : bh0;
  float iR[4], iZ[4], iN[4], iHh[4];
#pragma unroll
  for (int q = 0; q < 4; ++q) {
    int d = wid * 64 + q * 16 + (lane & 15);
    iR[q] = ldin(bI, d, f32w) + ldin(bH, d, f32w);
    iZ[q] = ldin(bI, 256 + d, f32w) + ldin(bH, 256 + d, f32w);
    iN[q] = ldin(bI, 512 + d, f32w);
    iHh[q] = ldin(bH, 512 + d, f32w);
  }

  float hst[2][4][4] = {};  // register h state: [m][q][j]

  if (!isL1) {
    // =========================== L0 pipeline ===========================
    for (int t = 0; t < 64; ++t) {
      const int slot = t & (RDEPTH - 1);
      // backpressure: slot reused from step t-RDEPTH; need L1 drained it
      if (t >= RDEPTH && tid == 0) {
        const unsigned tgt = (unsigned)(t - RDEPTH + 1);
        while (__hip_atomic_load(consF, __ATOMIC_RELAXED,
                                 __HIP_MEMORY_SCOPE_AGENT) < tgt)
          __builtin_amdgcn_s_sleep(1);
      }
      __syncthreads();  // [A] also orders prior-step HT writes vs reads

      f32x4 aR[2][4], aZ[2][4], aN[2][4], aH[2][4];
#pragma unroll
      for (int m = 0; m < 2; ++m)
#pragma unroll
        for (int q = 0; q < 4; ++q) {
          aR[m][q] = (f32x4){iR[q], iR[q], iR[q], iR[q]};
          aZ[m][q] = (f32x4){iZ[q], iZ[q], iZ[q], iZ[q]};
          aN[m][q] = (f32x4){iN[q], iN[q], iN[q], iN[q]};
          aH[m][q] = (f32x4){iHh[q], iHh[q], iHh[q], iHh[q]};
        }

      // ---- gi0: x(t) @ wi0 (K=64, streamed B) -> aR/aZ/aN ----
#pragma unroll
      for (int kk = 0; kk < 2; ++kk) {
        union { u16x8 u; bf8 b; } A0, A1;
        size_t x0 = ((size_t)t * ROWS + rb + (lane & 15)) * 64 + kk * 32 + koff;
        size_t x1 = x0 + 16 * 64;
        if (f32w) {
          const float* xf = (const float*)x;
#pragma unroll
          for (int e = 0; e < 8; ++e) {
            A0.u[e] = f2b(xf[x0 + e]);
            A1.u[e] = f2b(xf[x1 + e]);
          }
        } else {
          A0.u = *(const u16x8*)((const unsigned short*)x + x0);
          A1.u = *(const u16x8*)((const unsigned short*)x + x1);
        }
#pragma unroll
        for (int q = 0; q < 4; ++q) {
          const int nbq = wid * 4 + q;
          bf8 Br = *(const bf8*)(pwi0 + (size_t)(0 * 16 + nbq) * 1024 + kk * 512 + lane * 8);
          bf8 Bz = *(const bf8*)(pwi0 + (size_t)(1 * 16 + nbq) * 1024 + kk * 512 + lane * 8);
          bf8 Bn = *(const bf8*)(pwi0 + (size_t)(2 * 16 + nbq) * 1024 + kk * 512 + lane * 8);
          aR[0][q] = MFMA16(A0.b, Br, aR[0][q]);
          aR[1][q] = MFMA16(A1.b, Br, aR[1][q]);
          aZ[0][q] = MFMA16(A0.b, Bz, aZ[0][q]);
          aZ[1][q] = MFMA16(A1.b, Bz, aZ[1][q]);
          aN[0][q] = MFMA16(A0.b, Bn, aN[0][q]);
          aN[1][q] = MFMA16(A1.b, Bn, aN[1][q]);
        }
      }
      // ---- gh0: h0(t-1) @ wh0 (A from own LDS) -> aR/aZ/aH (BUGFIX) ----
      if (t >= 1) {
#pragma unroll
        for (int kk = 0; kk < 8; ++kk) {
          bf8 A0 = *(const bf8*)(HT + (0 + (lane & 15)) * 264 + kk * 32 + koff);
          bf8 A1 = *(const bf8*)(HT + (16 + (lane & 15)) * 264 + kk * 32 + koff);
#pragma unroll
          for (int q = 0; q < 4; ++q) {
            const int nbq = wid * 4 + q;
            bf8 Br = *(const bf8*)(pwh0 + (size_t)(0 * 16 + nbq) * 4096 + kk * 512 + lane * 8);
            bf8 Bz = *(const bf8*)(pwh0 + (size_t)(1 * 16 + nbq) * 4096 + kk * 512 + lane * 8);
            bf8 Bn = *(const bf8*)(pwh0 + (size_t)(2 * 16 + nbq) * 4096 + kk * 512 + lane * 8);
            aR[0][q] = MFMA16(A0, Br, aR[0][q]);
            aR[1][q] = MFMA16(A1, Br, aR[1][q]);
            aZ[0][q] = MFMA16(A0, Bz, aZ[0][q]);
            aZ[1][q] = MFMA16(A1, Bz, aZ[1][q]);
            aH[0][q] = MFMA16(A0, Bn, aH[0][q]);   // <- aH, not aN
            aH[1][q] = MFMA16(A1, Bn, aH[1][q]);   // <- aH, not aN
          }
        }
      }
      __syncthreads();  // [B] all HT reads done before overwrite

      // ---- epilogue: gates -> h0(t) -> HT ----
#pragma unroll
      for (int m = 0; m < 2; ++m)
#pragma unroll
        for (int q = 0; q < 4; ++q)
#pragma unroll
          for (int j = 0; j < 4; ++j) {
            float r = sigm(aR[m][q][j]);
            float z = sigm(aZ[m][q][j]);
            float n = tanh_fast(aN[m][q][j] + r * aH[m][q][j]);
            float hv = (1.0f - z) * n + z * hst[m][q][j];
            hst[m][q][j] = hv;
            int rloc = m * 16 + rl + j;
            int d = wid * 64 + q * 16 + (lane & 15);
            HT[rloc * 264 + d] = f2b(hv);
            if (t == 63)
              stout(out, OUT_HID_OFF + (size_t)(rb + rloc) * HID + d, hv, f32w);
          }
      __syncthreads();  // [C] HT complete

      // ---- publish h0(t) A-frags to ring slot ----
      unsigned short* rs = ringp + slot * RSLOTU;
#pragma unroll
      for (int i = 0; i < 4; ++i) {
        int idx = tid + i * 256;
        int m = idx >> 9, kk = (idx >> 6) & 7, l2 = idx & 63;
        u32x4 v = *(const u32x4*)(HT + (m * 16 + (l2 & 15)) * 264 + kk * 32 +
                                  (l2 >> 4) * 8);
        st16c(rs + (m * 8 + kk) * 512 + l2 * 8, v, fast);
      }
      VMDRAIN;
      __syncthreads();  // [D] all waves' stores complete
      if (tid == 0)
        __hip_atomic_fetch_add(prodF, 1u, __ATOMIC_RELAXED,
                               __HIP_MEMORY_SCOPE_AGENT);
    }
  } else {
    // =========================== L1 pipeline ===========================
    for (int t = 0; t < 64; ++t) {
      const int slot = t & (RDEPTH - 1);
      if (tid == 0) {
        const unsigned tgt = (unsigned)(t + 1);
        while (__hip_atomic_load(prodF, __ATOMIC_RELAXED,
                                 __HIP_MEMORY_SCOPE_AGENT) < tgt)
          __builtin_amdgcn_s_sleep(1);
      }
      __syncthreads();  // [A] also orders prior-step HT writes vs reads

      // ---- load h0(t) A-frags from ring (coalesced 16B, one drain) ----
      bf8 A0r[8], A1r[8];
      {
        const unsigned short* rs = ringp + slot * RSLOTU;
#pragma unroll
        for (int kk = 0; kk < 8; ++kk) {
          A0r[kk] = ld16b(rs + (0 * 8 + kk) * 512 + lane * 8, fast);
          A1r[kk] = ld16b(rs + (1 * 8 + kk) * 512 + lane * 8, fast);
        }
        VMDRAIN;
      }
      __syncthreads();  // [A2] all waves drained their ring reads
      if (tid == 0)
        __hip_atomic_fetch_add(consF, 1u, __ATOMIC_RELAXED,
                               __HIP_MEMORY_SCOPE_AGENT);

      f32x4 aR[2][4], aZ[2][4], aN[2][4], aH[2][4];
#pragma unroll
      for (int m = 0; m < 2; ++m)
#pragma unroll
        for (int q = 0; q < 4; ++q) {
          aR[m][q] = (f32x4){iR[q], iR[q], iR[q], iR[q]};
          aZ[m][q] = (f32x4){iZ[q], iZ[q], iZ[q], iZ[q]};
          aN[m][q] = (f32x4){iN[q], iN[q], iN[q], iN[q]};
          aH[m][q] = (f32x4){iHh[q], iHh[q], iHh[q], iHh[q]};
        }

      // ---- gi1: h0(t) @ wi1 (A in regs) -> aR/aZ/aN ----
#pragma unroll
      for (int kk = 0; kk < 8; ++kk) {
#pragma unroll
        for (int q = 0; q < 4; ++q) {
          const int nbq = wid * 4 + q;
          bf8 Br = *(const bf8*)(pwi1 + (size_t)(0 * 16 + nbq) * 4096 + kk * 512 + lane * 8);
          bf8 Bz = *(const bf8*)(pwi1 + (size_t)(1 * 16 + nbq) * 4096 + kk * 512 + lane * 8);
          bf8 Bn = *(const bf8*)(pwi1 + (size_t)(2 * 16 + nbq) * 4096 + kk * 512 + lane * 8);
          aR[0][q] = MFMA16(A0r[kk], Br, aR[0][q]);
          aR[1][q] = MFMA16(A1r[kk], Br, aR[1][q]);
          aZ[0][q] = MFMA16(A0r[kk], Bz, aZ[0][q]);
          aZ[1][q] = MFMA16(A1r[kk], Bz, aZ[1][q]);
          aN[0][q] = MFMA16(A0r[kk], Bn, aN[0][q]);
          aN[1][q] = MFMA16(A1r[kk], Bn, aN[1][q]);
        }
      }
      // ---- gh1: h1(t-1) @ wh1 (A from own LDS) -> aR/aZ/aH (BUGFIX) ----
      if (t >= 1) {
#pragma unroll
        for (int kk = 0; kk < 8; ++kk) {
          bf8 A0 = *(const bf8*)(HT + (0 + (lane & 15)) * 264 + kk * 32 + koff);
          bf8 A1 = *(const bf8*)(HT + (16 + (lane & 15)) * 264 + kk * 32 + koff);
#pragma unroll
          for (int q = 0; q < 4; ++q) {
            const int nbq = wid * 4 + q;
            bf8 Br = *(const bf8*)(pwh1 + (size_t)(0 * 16 + nbq) * 4096 + kk * 512 + lane * 8);
            bf8 Bz = *(const bf8*)(pwh1 + (size_t)(1 * 16 + nbq) * 4096 + kk * 512 + lane * 8);
            bf8 Bn = *(const bf8*)(pwh1 + (size_t)(2 * 16 + nbq) * 4096 + kk * 512 + lane * 8);
            aR[0][q] = MFMA16(A0, Br, aR[0][q]);
            aR[1][q] = MFMA16(A1, Br, aR[1][q]);
            aZ[0][q] = MFMA16(A0, Bz, aZ[0][q]);
            aZ[1][q] = MFMA16(A1, Bz, aZ[1][q]);
            aH[0][q] = MFMA16(A0, Bn, aH[0][q]);   // <- aH, not aN
            aH[1][q] = MFMA16(A1, Bn, aH[1][q]);   // <- aH, not aN
          }
        }
      }
      __syncthreads();  // [B] all HT reads done before overwrite

      // ---- epilogue: gates -> h1(t) -> HT + out ----
#pragma unroll
      for (int m = 0; m < 2; ++m)
#pragma unroll
        for (int q = 0; q < 4; ++q)
#pragma unroll
          for (int j = 0; j < 4; ++j) {
            float r = sigm(aR[m][q][j]);
            float z = sigm(aZ[m][q][j]);
            float n = tanh_fast(aN[m][q][j] + r * aH[m][q][j]);
            float hv = (1.0f - z) * n + z * hst[m][q][j];
            hst[m][q][j] = hv;
            int rloc = m * 16 + rl + j;
            int d = wid * 64 + q * 16 + (lane & 15);
            HT[rloc * 264 + d] = f2b(hv);
            stout(out, ((size_t)t * ROWS + rb + rloc) * HID + d, hv, f32w);
            if (t == 63)
              stout(out, OUT_HID_OFF + (size_t)SLOT + (size_t)(rb + rloc) * HID + d,
                    hv, f32w);
          }
      // next-step [A] barrier orders HT writes vs next gh1 reads
    }
  }
}

// --------------------------- host launcher ---------------------------------
extern "C" void kernel_launch(void* const* d_in, const int* in_sizes, int n_in,
                              void* d_out, int out_size, void* d_ws, size_t ws_size,
                              hipStream_t stream) {
  (void)in_sizes; (void)n_in; (void)out_size; (void)ws_size;
  const void* x   = d_in[0];
  const void* wi0 = d_in[1];
  const void* wh0 = d_in[2];
  const void* bi0 = d_in[3];
  const void* bh0 = d_in[4];
  const void* wi1 = d_in[5];
  const void* wh1 = d_in[6];
  const void* bi1 = d_in[7];
  const void* bh1 = d_in[8];
  void* out = d_out;

  char* ws = (char*)d_ws;
  unsigned* flags = (unsigned*)ws;                                 // 64 x 256 B
  unsigned* flag  = (unsigned*)(ws + 16384);                       // dtype flag
  unsigned short* ring = (unsigned short*)(ws + 32768);            // 4 MB
  unsigned short* pwi0 = (unsigned short*)(ws + 32768 + 4194304);  // 96 KB
  unsigned short* pwh0 = pwi0 + 49152;                             // 384 KB
  unsigned short* pwi1 = pwh0 + 196608;                            // 384 KB
  unsigned short* pwh1 = pwi1 + 196608;                            // 384 KB

  // zero: flags (prod/cons/vote) + dtype flag. Ring is write-before-read
  // (L1 reads a slot only after prodF covers it).
  hipMemsetAsync(d_ws, 0, 16384 + 64, stream);

  probe_dtype<<<1, 64, 0, stream>>>((const unsigned short*)x, flag);

  pack_w<<<(48 * 2 * 64 + 255) / 256, 256, 0, stream>>>(wi0, pwi0, 2, flag);
  pack_w<<<(48 * 8 * 64 + 255) / 256, 256, 0, stream>>>(wh0, pwh0, 8, flag);
  pack_w<<<(48 * 8 * 64 + 255) / 256, 256, 0, stream>>>(wi1, pwi1, 8, flag);
  pack_w<<<(48 * 8 * 64 + 255) / 256, 256, 0, stream>>>(wh1, pwh1, 8, flag);

  void* kargs[] = {&x, &bi0, &bh0, &bi1, &bh1, &pwi0, &pwh0, &pwi1, &pwh1,
                   &out, &ring, &flags, &flag};
  hipError_t lerr = hipLaunchCooperativeKernel(
      (const void*)gru_main, dim3(128), dim3(256), kargs, 0, stream);
  if (lerr != hipSuccess) {
    (void)hipGetLastError();  // plain launch safe: 128 blocks (<=256 CUs, 1/CU
    // resources) all dispatch immediately; pairs are mutually independent.
    gru_main<<<dim3(128), dim3(256), 0, stream>>>(
        x, bi0, bh0, bi1, bh1, pwi0, pwh0, pwi1, pwh1,
        out, ring, flags, flag);
  }
}

// Round 16
// 758.427 us; speedup vs baseline: 5.6189x; 5.6189x over previous
//
#include <hip/hip_runtime.h>

// ---------------------------------------------------------------------------
// 2-layer GRU, H=256, seq=64, rows = B*N = 2048.
// Base = r10 (best, 704us): 64 XCD-local row-groups (32 rows) x 4 dim-slices
// = 256 WGs, grid 256 (1/CU). Staged fragment exchange, agent-relaxed atomics.
// NEW (r8-proven protocol + r10-proven mapping): SPLIT FLAGS + EARLY PUBLISH.
// Phase t: poll(flag0>=4t, flag1>=4(t-1)) -> stage ring0[sp]+ring1[sc] ->
//   L0 MFMAs (wh0) + L0 epilogue -> EMIT ring0 + flag0   <- critical chain ends
//   L1 MFMAs (wi1 from staged A, wh1) + epilogue -> emit ring1 + flag1
//   out-stores (off-chain).
// Slot safety: flag0>=4t => members finished phase-(t-1) STAGING (stage
// precedes L0-emit) => both ring slots overwrite-safe. h1 consumed at
// 2-phase lag => flag1 may lag a full phase without stalling anyone.
// ---------------------------------------------------------------------------

typedef __attribute__((ext_vector_type(8))) __bf16 bf8;
typedef __attribute__((ext_vector_type(8))) unsigned short u16x8;
typedef __attribute__((ext_vector_type(4))) float f32x4;

#define MFMA16(A, B, C) __builtin_amdgcn_mfma_f32_16x16x32_bf16((A), (B), (C), 0, 0, 0)

#define ROWS 2048
#define HID 256
#define NW 768
#define SLOT (ROWS * HID)                       // 524288
#define OUT_HID_OFF ((size_t)64 * ROWS * HID)   // 33554432
#define R0SLOT 524288                           // u16 per ring slot (64 g * 8192)

static __device__ __forceinline__ float b2f(unsigned short u) {
  union { unsigned u32; float f; } v;
  v.u32 = ((unsigned)u) << 16;
  return v.f;
}
static __device__ __forceinline__ unsigned short f2b(float f) {
  unsigned u = __float_as_uint(f);
  u += 0x7fffu + ((u >> 16) & 1u);  // RNE
  return (unsigned short)(u >> 16);
}
static __device__ __forceinline__ float sigm(float x) {
  return 1.0f / (1.0f + __expf(-x));
}
static __device__ __forceinline__ float tanh_fast(float x) {
  x = fminf(15.0f, fmaxf(-15.0f, x));
  float e = __expf(2.0f * x);
  return (e - 1.0f) / (e + 1.0f);
}
static __device__ __forceinline__ float ldin(const void* p, int i, int f32w) {
  return f32w ? ((const float*)p)[i] : b2f(((const unsigned short*)p)[i]);
}
static __device__ __forceinline__ void stout(void* p, size_t i, float v, int f32w) {
  if (f32w) ((float*)p)[i] = v;
  else ((unsigned short*)p)[i] = f2b(v);
}

// Coherent 16B load / store: relaxed agent-scope u64 atomic pairs (bypass
// stale L1; served at the coherence point — local L2 when producer and
// consumer share an XCD). Compiler-tracked vmcnt. (r10-proven; r13's sc0
// asm variant measured SLOWER — reverted.)
static __device__ __forceinline__ u16x8 ld_h16(const unsigned short* p) {
  union { unsigned long long q[2]; u16x8 b; } u;
  u.q[0] = __hip_atomic_load((const unsigned long long*)p, __ATOMIC_RELAXED,
                             __HIP_MEMORY_SCOPE_AGENT);
  u.q[1] = __hip_atomic_load((const unsigned long long*)(p + 4), __ATOMIC_RELAXED,
                             __HIP_MEMORY_SCOPE_AGENT);
  return u.b;
}
static __device__ __forceinline__ void st_h16(unsigned short* p, u16x8 v) {
  union { u16x8 s; unsigned long long q[2]; } u;
  u.s = v;
  __hip_atomic_store((unsigned long long*)p, u.q[0], __ATOMIC_RELAXED,
                     __HIP_MEMORY_SCOPE_AGENT);
  __hip_atomic_store((unsigned long long*)(p + 4), u.q[1], __ATOMIC_RELAXED,
                     __HIP_MEMORY_SCOPE_AGENT);
}

// --------------------------- dtype probe -----------------------------------
__global__ void probe_dtype(const unsigned short* x, unsigned* flag) {
  if (blockIdx.x != 0 || threadIdx.x != 0) return;
  int cnt = 0;
  for (int i = 0; i < 256; ++i) {
    float v = b2f(x[i]);
    if (v == v && fabsf(v) <= 8.0f) cnt++;
  }
  *flag = (cnt >= 250) ? 0u : 1u;  // 0 = bf16 world, 1 = f32 world
}

// --------------------------- weight pre-pack -------------------------------
// packed[nb][kk][lane][e] = W[kk*32 + (lane>>4)*8 + e][nb*16 + (lane&15)]
__global__ void pack_w(const void* __restrict__ W,
                       unsigned short* __restrict__ P, int KK,
                       const unsigned* __restrict__ flag) {
  int i = blockIdx.x * blockDim.x + threadIdx.x;
  int total = 48 * KK * 64;
  if (i >= total) return;
  int f32w = (int)*flag;
  int l = i & 63;
  int kk = (i >> 6) % KK;
  int nb = i / (64 * KK);
  int n = nb * 16 + (l & 15);
  int k0 = kk * 32 + (l >> 4) * 8;
  u16x8 tmp;
#pragma unroll
  for (int e = 0; e < 8; ++e) tmp[e] = f2b(ldin(W, (k0 + e) * NW + n, f32w));
  *(u16x8*)(P + (size_t)i * 8) = tmp;
}

// --------------------------- main kernel -----------------------------------
__global__ void __launch_bounds__(256, 1) gru_main(
    const void* __restrict__ x,
    const void* __restrict__ bi0, const void* __restrict__ bh0,
    const void* __restrict__ bi1, const void* __restrict__ bh1,
    const unsigned short* __restrict__ pwi0, const unsigned short* __restrict__ pwh0,
    const unsigned short* __restrict__ pwi1, const unsigned short* __restrict__ pwh1,
    void* __restrict__ out,
    unsigned short* __restrict__ ring0, unsigned short* __restrict__ ring1,
    unsigned* __restrict__ flags, const unsigned* __restrict__ flag) {
  // LDS: A-frag stage [2 layers][16 frags][512] + h transpose stage [2][32][72]
  __shared__ __align__(16) unsigned short AS[16384];   // 32 KB
  __shared__ __align__(16) unsigned short HS[2][2304]; // 9 KB

  const int f32w = (int)*flag;
  const int tid = threadIdx.x;
  const int lane = tid & 63;
  const int wid = tid >> 6;
  const int bid = blockIdx.x;
  const int g = bid & 63;      // row group (32 rows); members stride-64 bids
  const int slice = bid >> 6;  // dim slice (64 dims) — members share an XCD
  const int nb = slice * 4 + wid;          // wave's 16-col block (0..15)

  const int d = nb * 16 + (lane & 15);     // wave's gate dim for acc col
  const int rb = g * 32;
  const int arow = rb + (lane & 15);
  const int koff = (lane >> 4) * 8;
  const int rl = (lane >> 4) * 4;
  const int cl = wid * 16 + (lane & 15);   // local col in h-stage [0,64)

  unsigned* flag0p = flags + (size_t)g * 64;  // 256 B stride per group
  unsigned* flag1p = flag0p + 32;

  const unsigned short* xw  = pwi0 + (size_t)nb * 1024;  // wi0 frag base
  const unsigned short* w0  = pwh0 + (size_t)nb * 4096;  // wh0 frag base
  const unsigned short* w1i = pwi1 + (size_t)nb * 4096;  // wi1 frag base
  const unsigned short* w1h = pwh1 + (size_t)nb * 4096;  // wh1 frag base

  const float iR0 = ldin(bi0, d, f32w) + ldin(bh0, d, f32w);
  const float iZ0 = ldin(bi0, 256 + d, f32w) + ldin(bh0, 256 + d, f32w);
  const float iI0 = ldin(bi0, 512 + d, f32w);
  const float iH0 = ldin(bh0, 512 + d, f32w);
  const float iR1 = ldin(bi1, d, f32w) + ldin(bh1, d, f32w);
  const float iZ1 = ldin(bi1, 256 + d, f32w) + ldin(bh1, 256 + d, f32w);
  const float iI1 = ldin(bi1, 512 + d, f32w);
  const float iH1 = ldin(bh1, 512 + d, f32w);

  float h0p[2][4] = {{0, 0, 0, 0}, {0, 0, 0, 0}};
  float h1p[2][4] = {{0, 0, 0, 0}, {0, 0, 0, 0}};

  // emit-slot constants (one 16B ring store per thread per layer)
  const int ef = tid >> 7;              // rowfrag
  const int ekk = (tid >> 6) & 1;       // local kk within slice
  const int eln = tid & 63;
  const int ehs = (ef * 16 + (eln & 15)) * 72 + ekk * 32 + (eln >> 4) * 8;
  const size_t ero = (size_t)g * 8192 +
                     (size_t)(ef * 8 + slice * 2 + ekk) * 512 + eln * 8;

  for (int t = 0; t <= 64; ++t) {
    const int sc = t & 1;
    const int sp = sc ^ 1;

    f32x4 aR0[2], aZ0[2], aI0[2], aH0[2], aR1[2], aZ1[2], aI1[2], aH1[2];
#pragma unroll
    for (int f = 0; f < 2; ++f) {
      aR0[f] = (f32x4){iR0, iR0, iR0, iR0};
      aZ0[f] = (f32x4){iZ0, iZ0, iZ0, iZ0};
      aI0[f] = (f32x4){iI0, iI0, iI0, iI0};
      aH0[f] = (f32x4){iH0, iH0, iH0, iH0};
      aR1[f] = (f32x4){iR1, iR1, iR1, iR1};
      aZ1[f] = (f32x4){iZ1, iZ1, iZ1, iZ1};
      aI1[f] = (f32x4){iI1, iI1, iI1, iI1};
      aH1[f] = (f32x4){iH1, iH1, iH1, iH1};
    }

    // ---- x-GEMM prefetch (no group dependency) ----
    if (t < 64) {
      size_t xoff = ((size_t)t * ROWS + arow) * 64 + koff;
#pragma unroll
      for (int kk = 0; kk < 2; ++kk) {
        union { u16x8 u; bf8 b; } A0, A1;
        if (f32w) {
          const float* ab = (const float*)x + xoff;
#pragma unroll
          for (int e = 0; e < 8; ++e) {
            A0.u[e] = f2b(ab[kk * 32 + e]);
            A1.u[e] = f2b(ab[16 * 64 + kk * 32 + e]);
          }
        } else {
          const unsigned short* ab = (const unsigned short*)x + xoff;
          A0.u = *(const u16x8*)(ab + kk * 32);
          A1.u = *(const u16x8*)(ab + 16 * 64 + kk * 32);
        }
        const int lb = lane * 8;
        bf8 Br = *(const bf8*)(xw + 0 * 16384 + kk * 512 + lb);
        bf8 Bz = *(const bf8*)(xw + 1 * 16384 + kk * 512 + lb);
        bf8 Bn = *(const bf8*)(xw + 2 * 16384 + kk * 512 + lb);
        aR0[0] = MFMA16(A0.b, Br, aR0[0]);
        aR0[1] = MFMA16(A1.b, Br, aR0[1]);
        aZ0[0] = MFMA16(A0.b, Bz, aZ0[0]);
        aZ0[1] = MFMA16(A1.b, Bz, aZ0[1]);
        aI0[0] = MFMA16(A0.b, Bn, aI0[0]);
        aI0[1] = MFMA16(A1.b, Bn, aI0[1]);
      }
    }

    // ---- polls: flag0 (h0(t-1) published), flag1 (h1(t-2) published) ----
    if (tid == 0) {
      if (t >= 1) {
        const unsigned tgt = 4u * (unsigned)t;
        while (__hip_atomic_load(flag0p, __ATOMIC_RELAXED,
                                 __HIP_MEMORY_SCOPE_AGENT) < tgt)
          __builtin_amdgcn_s_sleep(1);
      }
      if (t >= 2) {
        const unsigned tgt = 4u * (unsigned)(t - 1);
        while (__hip_atomic_load(flag1p, __ATOMIC_RELAXED,
                                 __HIP_MEMORY_SCOPE_AGENT) < tgt)
          __builtin_amdgcn_s_sleep(1);
      }
    }
    __syncthreads();

    // ---- stage A-frags into LDS: coalesced coherent 16B loads, once/WG ----
    {
      const unsigned short* r0 = ring0 + (size_t)sp * R0SLOT + (size_t)g * 8192;
#pragma unroll
      for (int i = 0; i < 4; ++i) {
        int idx = tid + i * 256;
        int ff = idx >> 6, ln2 = idx & 63;
        *(u16x8*)(AS + ff * 512 + ln2 * 8) = ld_h16(r0 + ff * 512 + ln2 * 8);
      }
      if (t >= 2) {
        const unsigned short* r1 = ring1 + (size_t)sc * R0SLOT + (size_t)g * 8192;
#pragma unroll
        for (int i = 0; i < 4; ++i) {
          int idx = tid + i * 256;
          int ff = idx >> 6, ln2 = idx & 63;
          *(u16x8*)(AS + 8192 + ff * 512 + ln2 * 8) =
              ld_h16(r1 + ff * 512 + ln2 * 8);
        }
      }
    }
    __syncthreads();

    // ================= L0 (critical chain): h0(t-1) @ wh0 =================
    if (t < 64) {
#pragma unroll
      for (int kk = 0; kk < 8; ++kk) {
        const int lb = lane * 8;
        bf8 A0 = *(const bf8*)(AS + (0 * 8 + kk) * 512 + lb);
        bf8 A1 = *(const bf8*)(AS + (1 * 8 + kk) * 512 + lb);
        bf8 Br0 = *(const bf8*)(w0 + 0 * 65536 + kk * 512 + lb);
        bf8 Bz0 = *(const bf8*)(w0 + 1 * 65536 + kk * 512 + lb);
        bf8 Bn0 = *(const bf8*)(w0 + 2 * 65536 + kk * 512 + lb);
        aR0[0] = MFMA16(A0, Br0, aR0[0]);
        aR0[1] = MFMA16(A1, Br0, aR0[1]);
        aZ0[0] = MFMA16(A0, Bz0, aZ0[0]);
        aZ0[1] = MFMA16(A1, Bz0, aZ0[1]);
        aH0[0] = MFMA16(A0, Bn0, aH0[0]);
        aH0[1] = MFMA16(A1, Bn0, aH0[1]);
      }
      // ---- L0 epilogue -> HS[0] ----
#pragma unroll
      for (int f = 0; f < 2; ++f) {
#pragma unroll
        for (int j = 0; j < 4; ++j) {
          float r = sigm(aR0[f][j]);
          float z = sigm(aZ0[f][j]);
          float n = tanh_fast(aI0[f][j] + r * aH0[f][j]);
          float hv = (1.0f - z) * n + z * h0p[f][j];
          h0p[f][j] = hv;
          HS[0][(f * 16 + rl + j) * 72 + cl] = f2b(hv);
        }
      }
    }
    __syncthreads();  // HS[0] complete

    // ---- EARLY PUBLISH: emit ring0 + flag0 before any layer-1 work ----
    if (t < 64)
      st_h16(ring0 + (size_t)sc * R0SLOT + ero, *(const u16x8*)(&HS[0][ehs]));
    asm volatile("s_waitcnt vmcnt(0)" ::: "memory");
    __syncthreads();
    if (t < 64 && tid == 0)
      __hip_atomic_fetch_add(flag0p, 1u, __ATOMIC_RELAXED,
                             __HIP_MEMORY_SCOPE_AGENT);

    // ================= L1 (off-chain): gi1 + gh1 =================
    if (t >= 1) {
#pragma unroll
      for (int kk = 0; kk < 8; ++kk) {
        const int lb = lane * 8;
        bf8 A0 = *(const bf8*)(AS + (0 * 8 + kk) * 512 + lb);
        bf8 A1 = *(const bf8*)(AS + (1 * 8 + kk) * 512 + lb);
        bf8 Br1 = *(const bf8*)(w1i + 0 * 65536 + kk * 512 + lb);
        bf8 Bz1 = *(const bf8*)(w1i + 1 * 65536 + kk * 512 + lb);
        bf8 Bn1 = *(const bf8*)(w1i + 2 * 65536 + kk * 512 + lb);
        aR1[0] = MFMA16(A0, Br1, aR1[0]);
        aR1[1] = MFMA16(A1, Br1, aR1[1]);
        aZ1[0] = MFMA16(A0, Bz1, aZ1[0]);
        aZ1[1] = MFMA16(A1, Bz1, aZ1[1]);
        aI1[0] = MFMA16(A0, Bn1, aI1[0]);
        aI1[1] = MFMA16(A1, Bn1, aI1[1]);
      }
      if (t >= 2) {
#pragma unroll
        for (int kk = 0; kk < 8; ++kk) {
          const int lb = lane * 8;
          bf8 A0 = *(const bf8*)(AS + 8192 + (0 * 8 + kk) * 512 + lb);
          bf8 A1 = *(const bf8*)(AS + 8192 + (1 * 8 + kk) * 512 + lb);
          bf8 Br = *(const bf8*)(w1h + 0 * 65536 + kk * 512 + lb);
          bf8 Bz = *(const bf8*)(w1h + 1 * 65536 + kk * 512 + lb);
          bf8 Bn = *(const bf8*)(w1h + 2 * 65536 + kk * 512 + lb);
          aR1[0] = MFMA16(A0, Br, aR1[0]);
          aR1[1] = MFMA16(A1, Br, aR1[1]);
          aZ1[0] = MFMA16(A0, Bz, aZ1[0]);
          aZ1[1] = MFMA16(A1, Bz, aZ1[1]);
          aH1[0] = MFMA16(A0, Bn, aH1[0]);
          aH1[1] = MFMA16(A1, Bn, aH1[1]);
        }
      }
      // ---- L1 epilogue -> HS[1] ----
#pragma unroll
      for (int f = 0; f < 2; ++f) {
#pragma unroll
        for (int j = 0; j < 4; ++j) {
          float r = sigm(aR1[f][j]);
          float z = sigm(aZ1[f][j]);
          float n = tanh_fast(aI1[f][j] + r * aH1[f][j]);
          float hv = (1.0f - z) * n + z * h1p[f][j];
          h1p[f][j] = hv;
          HS[1][(f * 16 + rl + j) * 72 + cl] = f2b(hv);
        }
      }
    }
    __syncthreads();  // HS[1] complete

    if (t >= 1 && t < 64)
      st_h16(ring1 + (size_t)sp * R0SLOT + ero, *(const u16x8*)(&HS[1][ehs]));
    asm volatile("s_waitcnt vmcnt(0)" ::: "memory");
    __syncthreads();
    if (t >= 1 && t < 64 && tid == 0)
      __hip_atomic_fetch_add(flag1p, 1u, __ATOMIC_RELAXED,
                             __HIP_MEMORY_SCOPE_AGENT);

    // ---- post-arrival out-stores (off the inter-group critical path) ----
    if (t >= 1) {
      const int tm1 = t - 1;
#pragma unroll
      for (int f = 0; f < 2; ++f) {
#pragma unroll
        for (int j = 0; j < 4; ++j) {
          int row = rb + f * 16 + rl + j;
          stout(out, ((size_t)tm1 * ROWS + row) * HID + d, h1p[f][j], f32w);
          if (tm1 == 63)
            stout(out, OUT_HID_OFF + (size_t)SLOT + (size_t)row * HID + d,
                  h1p[f][j], f32w);
        }
      }
    }
    if (t == 63) {
#pragma unroll
      for (int f = 0; f < 2; ++f) {
#pragma unroll
        for (int j = 0; j < 4; ++j) {
          int row = rb + f * 16 + rl + j;
          stout(out, OUT_HID_OFF + (size_t)row * HID + d, h0p[f][j], f32w);
        }
      }
    }
  }
}

// --------------------------- host launcher ---------------------------------
extern "C" void kernel_launch(void* const* d_in, const int* in_sizes, int n_in,
                              void* d_out, int out_size, void* d_ws, size_t ws_size,
                              hipStream_t stream) {
  (void)in_sizes; (void)n_in; (void)out_size; (void)ws_size;
  const void* x   = d_in[0];
  const void* wi0 = d_in[1];
  const void* wh0 = d_in[2];
  const void* bi0 = d_in[3];
  const void* bh0 = d_in[4];
  const void* wi1 = d_in[5];
  const void* wh1 = d_in[6];
  const void* bi1 = d_in[7];
  const void* bh1 = d_in[8];
  void* out = d_out;

  char* ws = (char*)d_ws;
  unsigned* flags = (unsigned*)ws;                                  // 64 x 256 B
  unsigned* flag  = (unsigned*)(ws + 16384);                        // dtype flag
  unsigned short* ring0 = (unsigned short*)(ws + 32768);            // 2 MB
  unsigned short* ring1 = (unsigned short*)(ws + 32768 + 2097152);  // 2 MB
  unsigned short* pwi0 = (unsigned short*)(ws + 32768 + 4194304);   // 96 KB
  unsigned short* pwh0 = pwi0 + 49152;                              // 384 KB
  unsigned short* pwi1 = pwh0 + 196608;                             // 384 KB
  unsigned short* pwh1 = pwi1 + 196608;                             // 384 KB

  // zero: flags + dtype flag + ring0 (h0(-1)=0; t=0 stages ring0 zeros).
  // ring1 is written before first read (t>=2 guard).
  hipMemsetAsync(d_ws, 0, 32768 + 2097152, stream);

  probe_dtype<<<1, 64, 0, stream>>>((const unsigned short*)x, flag);

  pack_w<<<(48 * 2 * 64 + 255) / 256, 256, 0, stream>>>(wi0, pwi0, 2, flag);
  pack_w<<<(48 * 8 * 64 + 255) / 256, 256, 0, stream>>>(wh0, pwh0, 8, flag);
  pack_w<<<(48 * 8 * 64 + 255) / 256, 256, 0, stream>>>(wi1, pwi1, 8, flag);
  pack_w<<<(48 * 8 * 64 + 255) / 256, 256, 0, stream>>>(wh1, pwh1, 8, flag);

  void* kargs[] = {&x, &bi0, &bh0, &bi1, &bh1, &pwi0, &pwh0, &pwi1, &pwh1,
                   &out, &ring0, &ring1, &flags, &flag};
  hipError_t lerr = hipLaunchCooperativeKernel(
      (const void*)gru_main, dim3(256), dim3(256), kargs, 0, stream);
  if (lerr != hipSuccess) {
    (void)hipGetLastError();  // clear sticky error; plain launch is safe:
    // groups are independent; any dispatched subset makes forward progress
    // because group members never wait on WGs outside their own group.
    gru_main<<<dim3(256), dim3(256), 0, stream>>>(
        x, bi0, bh0, bi1, bh1, pwi0, pwh0, pwi1, pwh1,
        out, ring0, ring1, flags, flag);
  }
}